// Round 1
// 320.882 us; speedup vs baseline: 1.0211x; 1.0211x over previous
//
#include <hip/hip_runtime.h>

#define B_  32
#define LC_ 2048
#define LQ_ 256
#define D_  256
#define NEGH (-30000.0f)   // f16-safe mask value

typedef _Float16 f16;
typedef _Float16 f16x4 __attribute__((ext_vector_type(4)));
typedef _Float16 f16x8 __attribute__((ext_vector_type(8)));
typedef float    f32x4 __attribute__((ext_vector_type(4)));

// ---- K1: cast ctx->f16, qry->qry*wm f16; sc = ctx.wc, sq = qry.wq ----
__global__ __launch_bounds__(256) void k_prep(
    const float* __restrict__ ctx, const float* __restrict__ qry,
    const float* __restrict__ w0, f16* __restrict__ ctx16,
    f16* __restrict__ qrywm16, float* __restrict__ sc, float* __restrict__ sq)
{
    const int lane = threadIdx.x & 63;
    const int wave = threadIdx.x >> 6;
    const int row  = blockIdx.x * 4 + wave;
    const int NC = B_ * LC_;
    if (row < NC) {
        float4 v = *(const float4*)(ctx + (long long)row * D_ + lane * 4);
        f16x4 h; h[0] = (f16)v.x; h[1] = (f16)v.y; h[2] = (f16)v.z; h[3] = (f16)v.w;
        *(f16x4*)(ctx16 + (long long)row * D_ + lane * 4) = h;
        float4 wc = *(const float4*)(w0 + lane * 4);
        float s = v.x*wc.x + v.y*wc.y + v.z*wc.z + v.w*wc.w;
        #pragma unroll
        for (int off = 32; off > 0; off >>= 1) s += __shfl_down(s, off, 64);
        if (lane == 0) sc[row] = s;
    } else {
        int r = row - NC;
        float4 v = *(const float4*)(qry + (long long)r * D_ + lane * 4);
        float4 wm = *(const float4*)(w0 + 2 * D_ + lane * 4);
        f16x4 h;
        h[0] = (f16)(v.x * wm.x); h[1] = (f16)(v.y * wm.y);
        h[2] = (f16)(v.z * wm.z); h[3] = (f16)(v.w * wm.w);
        *(f16x4*)(qrywm16 + (long long)r * D_ + lane * 4) = h;
        float4 wq = *(const float4*)(w0 + D_ + lane * 4);
        float s = v.x*wq.x + v.y*wq.y + v.z*wq.z + v.w*wq.w;
        #pragma unroll
        for (int off = 32; off > 0; off >>= 1) s += __shfl_down(s, off, 64);
        if (lane == 0) sq[r] = s;
    }
}

// ---- K2: transpose qry fp32 [q][d] -> f16 Bcat[0:256] rows [d][q] ----
__global__ __launch_bounds__(256) void k_tq(
    const float* __restrict__ in, f16* __restrict__ out)
{
    __shared__ float tile[64 * 65];
    const int b = blockIdx.z;
    const int r0 = blockIdx.x * 64, c0 = blockIdx.y * 64;
    const int t = threadIdx.x;
    const float* ib = in + (long long)b * LQ_ * D_;
    #pragma unroll
    for (int p = 0; p < 4; ++p) {
        int r = (t >> 4) + p * 16;
        int cb = (t & 15) * 4;
        float4 v = *(const float4*)(ib + (long long)(r0 + r) * D_ + c0 + cb);
        tile[r * 65 + cb + 0] = v.x;
        tile[r * 65 + cb + 1] = v.y;
        tile[r * 65 + cb + 2] = v.z;
        tile[r * 65 + cb + 3] = v.w;
    }
    __syncthreads();
    f16* ob = out + (long long)b * 512 * LQ_;
    #pragma unroll
    for (int p = 0; p < 4; ++p) {
        int c = (t >> 4) + p * 16;
        int rb = (t & 15) * 4;
        f16x4 h;
        h[0] = (f16)tile[(rb + 0) * 65 + c];
        h[1] = (f16)tile[(rb + 1) * 65 + c];
        h[2] = (f16)tile[(rb + 2) * 65 + c];
        h[3] = (f16)tile[(rb + 3) * 65 + c];
        *(f16x4*)(ob + (long long)(c0 + c) * LQ_ + r0 + rb) = h;
    }
}

// ---- G1: sim16[c][q] = f16(ctx16 @ qrywm16^T + sc + sq, masked) ----
// block: 128c x 256q (full LQ); fused epilogue computes row stats
// (rowm, rowinvl) and per-128-row-chunk column partials (pm, pl),
// replacing the old k_s1 pass. Stats use the f16-ROUNDED values so the
// numerics exactly match the previous sim16-reread implementation.
#define LDA1 40
__global__ __launch_bounds__(256) void k_g1(
    const f16* __restrict__ ctx16, const f16* __restrict__ qrywm16,
    const float* __restrict__ sc, const float* __restrict__ sq,
    const int* __restrict__ cmask, const int* __restrict__ qmask,
    f16* __restrict__ sim16,
    float* __restrict__ rowm, float* __restrict__ rowinvl,
    float* __restrict__ pm, float* __restrict__ pl)
{
    __shared__ f16 As[128 * LDA1];
    __shared__ f16 Bs[256 * LDA1];
    __shared__ float rowpm[4][64], rowps[4][64];
    __shared__ float colpm[4][128], colps[4][128];
    __shared__ float rowmax_s[128], colmax_s[256];
    const int b = blockIdx.z;
    const int c0 = blockIdx.x * 128;
    const int t = threadIdx.x, lane = t & 63, wv = t >> 6;
    const int wm_off = (wv >> 1) * 64, wn_off = (wv & 1) * 128;
    const f16* Ab = ctx16 + ((long long)b * LC_ + c0) * D_;
    const f16* Bb = qrywm16 + (long long)b * LQ_ * D_;
    const int srow = t >> 2, scg = (t & 3) * 8;
    f32x4 acc[4][8] = {};
    for (int k0 = 0; k0 < D_; k0 += 32) {
        #pragma unroll
        for (int p = 0; p < 2; ++p) {
            int r = srow + p * 64;
            *(f16x8*)(As + r * LDA1 + scg) = *(const f16x8*)(Ab + (long long)r * D_ + k0 + scg);
        }
        #pragma unroll
        for (int p = 0; p < 4; ++p) {
            int r = srow + p * 64;
            *(f16x8*)(Bs + r * LDA1 + scg) = *(const f16x8*)(Bb + (long long)r * D_ + k0 + scg);
        }
        __syncthreads();
        f16x8 af[4], bf[8];
        #pragma unroll
        for (int i = 0; i < 4; ++i)
            af[i] = *(const f16x8*)(As + (wm_off + i * 16 + (lane & 15)) * LDA1 + (lane >> 4) * 8);
        #pragma unroll
        for (int j = 0; j < 8; ++j)
            bf[j] = *(const f16x8*)(Bs + (wn_off + j * 16 + (lane & 15)) * LDA1 + (lane >> 4) * 8);
        #pragma unroll
        for (int i = 0; i < 4; ++i)
            #pragma unroll
            for (int j = 0; j < 8; ++j)
                acc[i][j] = __builtin_amdgcn_mfma_f32_16x16x32_f16(af[i], bf[j], acc[i][j], 0, 0, 0);
        __syncthreads();
    }
    // ---- epilogue: write sim16 + fused row/col softmax stats ----
    float sqv[8]; int qmv[8];
    #pragma unroll
    for (int j = 0; j < 8; ++j) {
        int q = wn_off + j * 16 + (lane & 15);
        sqv[j] = sq[b * LQ_ + q];
        qmv[j] = qmask[b * LQ_ + q];
    }
    float scv_[4][4]; int cmv_[4][4];
    #pragma unroll
    for (int i = 0; i < 4; ++i)
        #pragma unroll
        for (int r = 0; r < 4; ++r) {
            int c = c0 + wm_off + i * 16 + (lane >> 4) * 4 + r;
            scv_[i][r] = sc[b * LC_ + c];
            cmv_[i][r] = cmask[b * LC_ + c];
        }
    float rmax[4][4], cmax[8];
    #pragma unroll
    for (int i = 0; i < 4; ++i)
        #pragma unroll
        for (int r = 0; r < 4; ++r) rmax[i][r] = -INFINITY;
    #pragma unroll
    for (int j = 0; j < 8; ++j) cmax[j] = -INFINITY;
    // pass 1: rounded value -> store sim16, track row/col max
    #pragma unroll
    for (int i = 0; i < 4; ++i) {
        #pragma unroll
        for (int r = 0; r < 4; ++r) {
            int c = c0 + wm_off + i * 16 + (lane >> 4) * 4 + r;
            f16* orow = sim16 + ((long long)b * LC_ + c) * LQ_ + wn_off + (lane & 15);
            #pragma unroll
            for (int j = 0; j < 8; ++j) {
                float val = (cmv_[i][r] | qmv[j]) ? NEGH : (acc[i][j][r] + scv_[i][r] + sqv[j]);
                f16 hh = (f16)val;
                orow[j * 16] = hh;
                float vr = (float)hh;
                rmax[i][r] = fmaxf(rmax[i][r], vr);
                cmax[j]    = fmaxf(cmax[j], vr);
            }
        }
    }
    // reduce maxes: rows across lane&15, cols across lane>>4
    #pragma unroll
    for (int i = 0; i < 4; ++i)
        #pragma unroll
        for (int r = 0; r < 4; ++r) {
            rmax[i][r] = fmaxf(rmax[i][r], __shfl_xor(rmax[i][r], 1, 64));
            rmax[i][r] = fmaxf(rmax[i][r], __shfl_xor(rmax[i][r], 2, 64));
            rmax[i][r] = fmaxf(rmax[i][r], __shfl_xor(rmax[i][r], 4, 64));
            rmax[i][r] = fmaxf(rmax[i][r], __shfl_xor(rmax[i][r], 8, 64));
        }
    #pragma unroll
    for (int j = 0; j < 8; ++j) {
        cmax[j] = fmaxf(cmax[j], __shfl_xor(cmax[j], 16, 64));
        cmax[j] = fmaxf(cmax[j], __shfl_xor(cmax[j], 32, 64));
    }
    if ((lane & 15) == 0) {
        #pragma unroll
        for (int i = 0; i < 4; ++i)
            #pragma unroll
            for (int r = 0; r < 4; ++r)
                rowpm[wv][i * 16 + (lane >> 4) * 4 + r] = rmax[i][r];
    }
    if (lane < 16) {
        #pragma unroll
        for (int j = 0; j < 8; ++j) colpm[wv][j * 16 + lane] = cmax[j];
    }
    __syncthreads();
    if (t < 128)
        rowmax_s[t] = fmaxf(rowpm[2 * (t >> 6)][t & 63], rowpm[2 * (t >> 6) + 1][t & 63]);
    colmax_s[t] = fmaxf(colpm[t >> 7][t & 127], colpm[(t >> 7) + 2][t & 127]);
    __syncthreads();
    // pass 2: sums of exp(v - max)
    float rmf[4][4], cmf[8];
    #pragma unroll
    for (int i = 0; i < 4; ++i)
        #pragma unroll
        for (int r = 0; r < 4; ++r)
            rmf[i][r] = rowmax_s[wm_off + i * 16 + (lane >> 4) * 4 + r];
    #pragma unroll
    for (int j = 0; j < 8; ++j) cmf[j] = colmax_s[wn_off + j * 16 + (lane & 15)];
    float rsum[4][4] = {}, csum[8] = {};
    #pragma unroll
    for (int i = 0; i < 4; ++i) {
        #pragma unroll
        for (int r = 0; r < 4; ++r) {
            #pragma unroll
            for (int j = 0; j < 8; ++j) {
                float val = (cmv_[i][r] | qmv[j]) ? NEGH : (acc[i][j][r] + scv_[i][r] + sqv[j]);
                float vr = (float)(f16)val;
                rsum[i][r] += __expf(vr - rmf[i][r]);
                csum[j]    += __expf(vr - cmf[j]);
            }
        }
    }
    #pragma unroll
    for (int i = 0; i < 4; ++i)
        #pragma unroll
        for (int r = 0; r < 4; ++r) {
            rsum[i][r] += __shfl_xor(rsum[i][r], 1, 64);
            rsum[i][r] += __shfl_xor(rsum[i][r], 2, 64);
            rsum[i][r] += __shfl_xor(rsum[i][r], 4, 64);
            rsum[i][r] += __shfl_xor(rsum[i][r], 8, 64);
        }
    #pragma unroll
    for (int j = 0; j < 8; ++j) {
        csum[j] += __shfl_xor(csum[j], 16, 64);
        csum[j] += __shfl_xor(csum[j], 32, 64);
    }
    if ((lane & 15) == 0) {
        #pragma unroll
        for (int i = 0; i < 4; ++i)
            #pragma unroll
            for (int r = 0; r < 4; ++r)
                rowps[wv][i * 16 + (lane >> 4) * 4 + r] = rsum[i][r];
    }
    if (lane < 16) {
        #pragma unroll
        for (int j = 0; j < 8; ++j) colps[wv][j * 16 + lane] = csum[j];
    }
    __syncthreads();
    if (t < 128) {
        float l = rowps[2 * (t >> 6)][t & 63] + rowps[2 * (t >> 6) + 1][t & 63];
        rowm[b * LC_ + c0 + t]    = rowmax_s[t];
        rowinvl[b * LC_ + c0 + t] = 1.0f / l;
    }
    {
        int idx = (b * 16 + blockIdx.x) * LQ_ + t;
        pm[idx] = colmax_s[t];
        pl[idx] = colps[t >> 7][t & 127] + colps[(t >> 7) + 2][t & 127];
    }
}

__global__ __launch_bounds__(256) void k_colreduce(
    const float* __restrict__ pm, const float* __restrict__ pl,
    float* __restrict__ colm, float* __restrict__ colinvl)
{
    const int col = blockIdx.x * 256 + threadIdx.x;
    const int b = col >> 8, q = col & 255;
    float M = -INFINITY, L = 0.f;
    for (int ch = 0; ch < 16; ++ch) {
        int idx = (b * 16 + ch) * LQ_ + q;
        float m = pm[idx], l = pl[idx];
        float nM = fmaxf(M, m);
        L = L * __expf(M - nM) + l * __expf(m - nM);
        M = nM;
    }
    colm[col] = M; colinvl[col] = 1.0f / L;
}

// ---- G3: Tt[d][q] = colinvl[q] * sum_c ctx[c][d]*exp(sim[c][q]-colm[q]) ----
// -> Bcat[256+d][q] f16.  Both operands LDS-transposed at staging.
#define LDA3 66
__global__ __launch_bounds__(256) void k_g3(
    const f16* __restrict__ ctx16, const f16* __restrict__ sim16,
    const float* __restrict__ colm, const float* __restrict__ colinvl,
    f16* __restrict__ Bcat)
{
    __shared__ f16 As[128 * LDA3];   // [d][c]
    __shared__ f16 Bs[64 * LDA3];    // [q][c]
    __shared__ float colm_s[64], cil_s[64];
    const int b = blockIdx.x;
    const int combo = blockIdx.y;          // qt(0..3) + 4*dh(0..1)
    const int qt = combo & 3, dh = combo >> 2;
    const int q0 = qt * 64, d0 = dh * 128;
    const int t = threadIdx.x, lane = t & 63, wv = t >> 6;
    const int wm_off = (wv >> 1) * 64, wn_off = (wv & 1) * 32;
    if (t < 64) {
        colm_s[t] = colm[b * LQ_ + q0 + t];
        cil_s[t]  = colinvl[b * LQ_ + q0 + t];
    }
    __syncthreads();
    const f16* Ab = ctx16 + (long long)b * LC_ * D_;
    const f16* Sb = sim16 + (long long)b * LC_ * LQ_;
    f32x4 acc[4][2] = {};
    const int acc_ = t >> 4, ad8 = (t & 15) * 8;   // A staging: c-row, d-col8
    const int bcc = t >> 3, bq8 = (t & 7) * 8;     // B staging: c-row, q-col8
    for (int c0 = 0; c0 < LC_; c0 += 64) {
        #pragma unroll
        for (int p = 0; p < 4; ++p) {
            int cc = acc_ + p * 16;
            f16x8 h = *(const f16x8*)(Ab + (long long)(c0 + cc) * D_ + d0 + ad8);
            #pragma unroll
            for (int j = 0; j < 8; ++j)
                As[(ad8 + j) * LDA3 + cc] = h[j];
        }
        #pragma unroll
        for (int p = 0; p < 2; ++p) {
            int cc = bcc + p * 32;
            f16x8 h = *(const f16x8*)(Sb + (long long)(c0 + cc) * LQ_ + q0 + bq8);
            #pragma unroll
            for (int j = 0; j < 8; ++j)
                Bs[(bq8 + j) * LDA3 + cc] = (f16)__expf((float)h[j] - colm_s[bq8 + j]);
        }
        __syncthreads();
        #pragma unroll
        for (int kk = 0; kk < 64; kk += 32) {
            f16x8 af[4], bf[2];
            #pragma unroll
            for (int i = 0; i < 4; ++i)
                af[i] = *(const f16x8*)(As + (wm_off + i * 16 + (lane & 15)) * LDA3 + kk + (lane >> 4) * 8);
            #pragma unroll
            for (int j = 0; j < 2; ++j)
                bf[j] = *(const f16x8*)(Bs + (wn_off + j * 16 + (lane & 15)) * LDA3 + kk + (lane >> 4) * 8);
            #pragma unroll
            for (int i = 0; i < 4; ++i)
                #pragma unroll
                for (int j = 0; j < 2; ++j)
                    acc[i][j] = __builtin_amdgcn_mfma_f32_16x16x32_f16(af[i], bf[j], acc[i][j], 0, 0, 0);
        }
        __syncthreads();
    }
    #pragma unroll
    for (int i = 0; i < 4; ++i) {
        #pragma unroll
        for (int r = 0; r < 4; ++r) {
            int d = d0 + wm_off + i * 16 + (lane >> 4) * 4 + r;
            f16* orow = Bcat + (long long)b * 512 * LQ_ + (long long)(256 + d) * LQ_ + q0 + wn_off + (lane & 15);
            #pragma unroll
            for (int j = 0; j < 2; ++j)
                orow[j * 16] = (f16)(acc[i][j][r] * cil_s[wn_off + j * 16 + (lane & 15)]);
        }
    }
}

// ---- G23: [A | Bmat] = rowinvl * exp(sim16 - rowm) @ Bcat^T ----
// 256c x 256n tile, 512 threads (8 waves, 2x4): halves sim16 and Bcat
// re-reads vs the old 128x128 tiling (396 MB -> 262 MB total traffic).
__global__ __launch_bounds__(512) void k_g23(
    const f16* __restrict__ sim16, const float* __restrict__ rowm,
    const float* __restrict__ rowinvl, const f16* __restrict__ Bcat,
    float* __restrict__ outA, float* __restrict__ outB)
{
    __shared__ f16 As[256 * LDA1];
    __shared__ f16 Bs[256 * LDA1];
    const int b = blockIdx.z;
    const int c0 = blockIdx.x * 256, n0 = blockIdx.y * 256;
    const int t = threadIdx.x, lane = t & 63, wv = t >> 6;   // wv 0..7
    const int wm_off = (wv >> 2) * 128;      // 0 or 128
    const int wn_off = (wv & 3) * 64;        // 0,64,128,192
    const f16* Ab = sim16 + ((long long)b * LC_ + c0) * LQ_;
    const f16* Bb = Bcat + ((long long)b * 512 + n0) * LQ_;
    const int srow = t >> 2, scg = (t & 3) * 8;   // srow 0..127
    float rm[2];
    #pragma unroll
    for (int p = 0; p < 2; ++p) rm[p] = rowm[b * LC_ + c0 + srow + p * 128];
    f32x4 acc[8][4] = {};
    for (int k0 = 0; k0 < LQ_; k0 += 32) {
        #pragma unroll
        for (int p = 0; p < 2; ++p) {
            int r = srow + p * 128;
            f16x8 h = *(const f16x8*)(Ab + (long long)r * LQ_ + k0 + scg);
            f16x8 e;
            #pragma unroll
            for (int j = 0; j < 8; ++j) e[j] = (f16)__expf((float)h[j] - rm[p]);
            *(f16x8*)(As + r * LDA1 + scg) = e;
            *(f16x8*)(Bs + r * LDA1 + scg) = *(const f16x8*)(Bb + (long long)r * LQ_ + k0 + scg);
        }
        __syncthreads();
        f16x8 bf[4];
        #pragma unroll
        for (int j = 0; j < 4; ++j)
            bf[j] = *(const f16x8*)(Bs + (wn_off + j * 16 + (lane & 15)) * LDA1 + (lane >> 4) * 8);
        #pragma unroll
        for (int i = 0; i < 8; ++i) {
            f16x8 af = *(const f16x8*)(As + (wm_off + i * 16 + (lane & 15)) * LDA1 + (lane >> 4) * 8);
            #pragma unroll
            for (int j = 0; j < 4; ++j)
                acc[i][j] = __builtin_amdgcn_mfma_f32_16x16x32_f16(af, bf[j], acc[i][j], 0, 0, 0);
        }
        __syncthreads();
    }
    float* outp = (n0 == 0) ? outA : outB;
    #pragma unroll
    for (int i = 0; i < 8; ++i) {
        #pragma unroll
        for (int r = 0; r < 4; ++r) {
            int c = c0 + wm_off + i * 16 + (lane >> 4) * 4 + r;
            float ri = rowinvl[b * LC_ + c];
            float* orow = outp + ((long long)b * LC_ + c) * D_ + wn_off + (lane & 15);
            #pragma unroll
            for (int j = 0; j < 4; ++j)
                orow[j * 16] = acc[i][j][r] * ri;
        }
    }
}

extern "C" void kernel_launch(void* const* d_in, const int* in_sizes, int n_in,
                              void* d_out, int out_size, void* d_ws, size_t ws_size,
                              hipStream_t stream) {
    const float* ctx   = (const float*)d_in[0];
    const float* qry   = (const float*)d_in[1];
    const int*   cmask = (const int*)d_in[2];
    const int*   qmask = (const int*)d_in[3];
    const float* w0    = (const float*)d_in[4];
    float* out = (float*)d_out;

    char* w = (char*)d_ws;
    float* sc      = (float*)w;  w += (long long)65536 * 4;
    float* sq      = (float*)w;  w += (long long)8192 * 4;
    float* rowm    = (float*)w;  w += (long long)65536 * 4;
    float* rowinvl = (float*)w;  w += (long long)65536 * 4;
    float* colm    = (float*)w;  w += (long long)8192 * 4;
    float* colinvl = (float*)w;  w += (long long)8192 * 4;
    float* pm      = (float*)w;  w += (long long)524288 * 4;
    float* pl      = (float*)w;  w += (long long)524288 * 4;
    f16*   sim16   = (f16*)w;    w += (long long)16777216 * 2;
    f16*   ctx16   = (f16*)w;    w += (long long)16777216 * 2;
    f16*   qrywm16 = (f16*)w;    w += (long long)2097152 * 2;
    f16*   Bcat    = (f16*)w;    w += (long long)4194304 * 2;

    k_prep<<<18432, 256, 0, stream>>>(ctx, qry, w0, ctx16, qrywm16, sc, sq);
    k_tq<<<dim3(4, 4, 32), 256, 0, stream>>>(qry, Bcat);
    k_g1<<<dim3(16, 1, 32), 256, 0, stream>>>(ctx16, qrywm16, sc, sq, cmask, qmask,
        sim16, rowm, rowinvl, pm, pl);
    k_colreduce<<<32, 256, 0, stream>>>(pm, pl, colm, colinvl);
    k_g3<<<dim3(32, 8), 256, 0, stream>>>(ctx16, sim16, colm, colinvl, Bcat);
    k_g23<<<dim3(8, 2, 32), 512, 0, stream>>>(sim16, rowm, rowinvl, Bcat,
        out, out + (long long)B_ * LC_ * D_);
}

// Round 2
// 309.823 us; speedup vs baseline: 1.0575x; 1.0357x over previous
//
#include <hip/hip_runtime.h>

#define B_  32
#define LC_ 2048
#define LQ_ 256
#define D_  256
#define NEGH (-30000.0f)   // f16-safe mask value

typedef _Float16 f16;
typedef _Float16 f16x4 __attribute__((ext_vector_type(4)));
typedef _Float16 f16x8 __attribute__((ext_vector_type(8)));
typedef float    f32x4 __attribute__((ext_vector_type(4)));

// ---- K1: cast ctx->f16, qry->qry*wm f16; sc = ctx.wc, sq = qry.wq ----
__global__ __launch_bounds__(256) void k_prep(
    const float* __restrict__ ctx, const float* __restrict__ qry,
    const float* __restrict__ w0, f16* __restrict__ ctx16,
    f16* __restrict__ qrywm16, float* __restrict__ sc, float* __restrict__ sq)
{
    const int lane = threadIdx.x & 63;
    const int wave = threadIdx.x >> 6;
    const int row  = blockIdx.x * 4 + wave;
    const int NC = B_ * LC_;
    if (row < NC) {
        float4 v = *(const float4*)(ctx + (long long)row * D_ + lane * 4);
        f16x4 h; h[0] = (f16)v.x; h[1] = (f16)v.y; h[2] = (f16)v.z; h[3] = (f16)v.w;
        *(f16x4*)(ctx16 + (long long)row * D_ + lane * 4) = h;
        float4 wc = *(const float4*)(w0 + lane * 4);
        float s = v.x*wc.x + v.y*wc.y + v.z*wc.z + v.w*wc.w;
        #pragma unroll
        for (int off = 32; off > 0; off >>= 1) s += __shfl_down(s, off, 64);
        if (lane == 0) sc[row] = s;
    } else {
        int r = row - NC;
        float4 v = *(const float4*)(qry + (long long)r * D_ + lane * 4);
        float4 wm = *(const float4*)(w0 + 2 * D_ + lane * 4);
        f16x4 h;
        h[0] = (f16)(v.x * wm.x); h[1] = (f16)(v.y * wm.y);
        h[2] = (f16)(v.z * wm.z); h[3] = (f16)(v.w * wm.w);
        *(f16x4*)(qrywm16 + (long long)r * D_ + lane * 4) = h;
        float4 wq = *(const float4*)(w0 + D_ + lane * 4);
        float s = v.x*wq.x + v.y*wq.y + v.z*wq.z + v.w*wq.w;
        #pragma unroll
        for (int off = 32; off > 0; off >>= 1) s += __shfl_down(s, off, 64);
        if (lane == 0) sq[r] = s;
    }
}

// ---- K2: transpose qry fp32 [q][d] -> f16 Bcat[0:256] rows [d][q] ----
__global__ __launch_bounds__(256) void k_tq(
    const float* __restrict__ in, f16* __restrict__ out)
{
    __shared__ float tile[64 * 65];
    const int b = blockIdx.z;
    const int r0 = blockIdx.x * 64, c0 = blockIdx.y * 64;
    const int t = threadIdx.x;
    const float* ib = in + (long long)b * LQ_ * D_;
    #pragma unroll
    for (int p = 0; p < 4; ++p) {
        int r = (t >> 4) + p * 16;
        int cb = (t & 15) * 4;
        float4 v = *(const float4*)(ib + (long long)(r0 + r) * D_ + c0 + cb);
        tile[r * 65 + cb + 0] = v.x;
        tile[r * 65 + cb + 1] = v.y;
        tile[r * 65 + cb + 2] = v.z;
        tile[r * 65 + cb + 3] = v.w;
    }
    __syncthreads();
    f16* ob = out + (long long)b * 512 * LQ_;
    #pragma unroll
    for (int p = 0; p < 4; ++p) {
        int c = (t >> 4) + p * 16;
        int rb = (t & 15) * 4;
        f16x4 h;
        h[0] = (f16)tile[(rb + 0) * 65 + c];
        h[1] = (f16)tile[(rb + 1) * 65 + c];
        h[2] = (f16)tile[(rb + 2) * 65 + c];
        h[3] = (f16)tile[(rb + 3) * 65 + c];
        *(f16x4*)(ob + (long long)(c0 + c) * LQ_ + r0 + rb) = h;
    }
}

// ---- G1: sim16[c][q] = f16(ctx16 @ qrywm16^T + sc + sq, masked) ----
// block: 128c x 256q (full LQ); fused epilogue computes row stats
// (rowm, rowinvl) and per-128-row-chunk column partials (pm, pl).
#define LDA1 40
__global__ __launch_bounds__(256) void k_g1(
    const f16* __restrict__ ctx16, const f16* __restrict__ qrywm16,
    const float* __restrict__ sc, const float* __restrict__ sq,
    const int* __restrict__ cmask, const int* __restrict__ qmask,
    f16* __restrict__ sim16,
    float* __restrict__ rowm, float* __restrict__ rowinvl,
    float* __restrict__ pm, float* __restrict__ pl)
{
    __shared__ f16 As[128 * LDA1];
    __shared__ f16 Bs[256 * LDA1];
    __shared__ float rowpm[4][64], rowps[4][64];
    __shared__ float colpm[4][128], colps[4][128];
    __shared__ float rowmax_s[128], colmax_s[256];
    const int b = blockIdx.z;
    const int c0 = blockIdx.x * 128;
    const int t = threadIdx.x, lane = t & 63, wv = t >> 6;
    const int wm_off = (wv >> 1) * 64, wn_off = (wv & 1) * 128;
    const f16* Ab = ctx16 + ((long long)b * LC_ + c0) * D_;
    const f16* Bb = qrywm16 + (long long)b * LQ_ * D_;
    const int srow = t >> 2, scg = (t & 3) * 8;
    f32x4 acc[4][8] = {};
    for (int k0 = 0; k0 < D_; k0 += 32) {
        #pragma unroll
        for (int p = 0; p < 2; ++p) {
            int r = srow + p * 64;
            *(f16x8*)(As + r * LDA1 + scg) = *(const f16x8*)(Ab + (long long)r * D_ + k0 + scg);
        }
        #pragma unroll
        for (int p = 0; p < 4; ++p) {
            int r = srow + p * 64;
            *(f16x8*)(Bs + r * LDA1 + scg) = *(const f16x8*)(Bb + (long long)r * D_ + k0 + scg);
        }
        __syncthreads();
        f16x8 af[4], bf[8];
        #pragma unroll
        for (int i = 0; i < 4; ++i)
            af[i] = *(const f16x8*)(As + (wm_off + i * 16 + (lane & 15)) * LDA1 + (lane >> 4) * 8);
        #pragma unroll
        for (int j = 0; j < 8; ++j)
            bf[j] = *(const f16x8*)(Bs + (wn_off + j * 16 + (lane & 15)) * LDA1 + (lane >> 4) * 8);
        #pragma unroll
        for (int i = 0; i < 4; ++i)
            #pragma unroll
            for (int j = 0; j < 8; ++j)
                acc[i][j] = __builtin_amdgcn_mfma_f32_16x16x32_f16(af[i], bf[j], acc[i][j], 0, 0, 0);
        __syncthreads();
    }
    // ---- epilogue: write sim16 + fused row/col softmax stats ----
    float sqv[8]; int qmv[8];
    #pragma unroll
    for (int j = 0; j < 8; ++j) {
        int q = wn_off + j * 16 + (lane & 15);
        sqv[j] = sq[b * LQ_ + q];
        qmv[j] = qmask[b * LQ_ + q];
    }
    float scv_[4][4]; int cmv_[4][4];
    #pragma unroll
    for (int i = 0; i < 4; ++i)
        #pragma unroll
        for (int r = 0; r < 4; ++r) {
            int c = c0 + wm_off + i * 16 + (lane >> 4) * 4 + r;
            scv_[i][r] = sc[b * LC_ + c];
            cmv_[i][r] = cmask[b * LC_ + c];
        }
    float rmax[4][4], cmax[8];
    #pragma unroll
    for (int i = 0; i < 4; ++i)
        #pragma unroll
        for (int r = 0; r < 4; ++r) rmax[i][r] = -INFINITY;
    #pragma unroll
    for (int j = 0; j < 8; ++j) cmax[j] = -INFINITY;
    #pragma unroll
    for (int i = 0; i < 4; ++i) {
        #pragma unroll
        for (int r = 0; r < 4; ++r) {
            int c = c0 + wm_off + i * 16 + (lane >> 4) * 4 + r;
            f16* orow = sim16 + ((long long)b * LC_ + c) * LQ_ + wn_off + (lane & 15);
            #pragma unroll
            for (int j = 0; j < 8; ++j) {
                float val = (cmv_[i][r] | qmv[j]) ? NEGH : (acc[i][j][r] + scv_[i][r] + sqv[j]);
                f16 hh = (f16)val;
                orow[j * 16] = hh;
                float vr = (float)hh;
                rmax[i][r] = fmaxf(rmax[i][r], vr);
                cmax[j]    = fmaxf(cmax[j], vr);
            }
        }
    }
    #pragma unroll
    for (int i = 0; i < 4; ++i)
        #pragma unroll
        for (int r = 0; r < 4; ++r) {
            rmax[i][r] = fmaxf(rmax[i][r], __shfl_xor(rmax[i][r], 1, 64));
            rmax[i][r] = fmaxf(rmax[i][r], __shfl_xor(rmax[i][r], 2, 64));
            rmax[i][r] = fmaxf(rmax[i][r], __shfl_xor(rmax[i][r], 4, 64));
            rmax[i][r] = fmaxf(rmax[i][r], __shfl_xor(rmax[i][r], 8, 64));
        }
    #pragma unroll
    for (int j = 0; j < 8; ++j) {
        cmax[j] = fmaxf(cmax[j], __shfl_xor(cmax[j], 16, 64));
        cmax[j] = fmaxf(cmax[j], __shfl_xor(cmax[j], 32, 64));
    }
    if ((lane & 15) == 0) {
        #pragma unroll
        for (int i = 0; i < 4; ++i)
            #pragma unroll
            for (int r = 0; r < 4; ++r)
                rowpm[wv][i * 16 + (lane >> 4) * 4 + r] = rmax[i][r];
    }
    if (lane < 16) {
        #pragma unroll
        for (int j = 0; j < 8; ++j) colpm[wv][j * 16 + lane] = cmax[j];
    }
    __syncthreads();
    if (t < 128)
        rowmax_s[t] = fmaxf(rowpm[2 * (t >> 6)][t & 63], rowpm[2 * (t >> 6) + 1][t & 63]);
    colmax_s[t] = fmaxf(colpm[t >> 7][t & 127], colpm[(t >> 7) + 2][t & 127]);
    __syncthreads();
    float rmf[4][4], cmf[8];
    #pragma unroll
    for (int i = 0; i < 4; ++i)
        #pragma unroll
        for (int r = 0; r < 4; ++r)
            rmf[i][r] = rowmax_s[wm_off + i * 16 + (lane >> 4) * 4 + r];
    #pragma unroll
    for (int j = 0; j < 8; ++j) cmf[j] = colmax_s[wn_off + j * 16 + (lane & 15)];
    float rsum[4][4] = {}, csum[8] = {};
    #pragma unroll
    for (int i = 0; i < 4; ++i) {
        #pragma unroll
        for (int r = 0; r < 4; ++r) {
            #pragma unroll
            for (int j = 0; j < 8; ++j) {
                float val = (cmv_[i][r] | qmv[j]) ? NEGH : (acc[i][j][r] + scv_[i][r] + sqv[j]);
                float vr = (float)(f16)val;
                rsum[i][r] += __expf(vr - rmf[i][r]);
                csum[j]    += __expf(vr - cmf[j]);
            }
        }
    }
    #pragma unroll
    for (int i = 0; i < 4; ++i)
        #pragma unroll
        for (int r = 0; r < 4; ++r) {
            rsum[i][r] += __shfl_xor(rsum[i][r], 1, 64);
            rsum[i][r] += __shfl_xor(rsum[i][r], 2, 64);
            rsum[i][r] += __shfl_xor(rsum[i][r], 4, 64);
            rsum[i][r] += __shfl_xor(rsum[i][r], 8, 64);
        }
    #pragma unroll
    for (int j = 0; j < 8; ++j) {
        csum[j] += __shfl_xor(csum[j], 16, 64);
        csum[j] += __shfl_xor(csum[j], 32, 64);
    }
    if ((lane & 15) == 0) {
        #pragma unroll
        for (int i = 0; i < 4; ++i)
            #pragma unroll
            for (int r = 0; r < 4; ++r)
                rowps[wv][i * 16 + (lane >> 4) * 4 + r] = rsum[i][r];
    }
    if (lane < 16) {
        #pragma unroll
        for (int j = 0; j < 8; ++j) colps[wv][j * 16 + lane] = csum[j];
    }
    __syncthreads();
    if (t < 128) {
        float l = rowps[2 * (t >> 6)][t & 63] + rowps[2 * (t >> 6) + 1][t & 63];
        rowm[b * LC_ + c0 + t]    = rowmax_s[t];
        rowinvl[b * LC_ + c0 + t] = 1.0f / l;
    }
    {
        int idx = (b * 16 + blockIdx.x) * LQ_ + t;
        pm[idx] = colmax_s[t];
        pl[idx] = colps[t >> 7][t & 127] + colps[(t >> 7) + 2][t & 127];
    }
}

__global__ __launch_bounds__(256) void k_colreduce(
    const float* __restrict__ pm, const float* __restrict__ pl,
    float* __restrict__ colm, float* __restrict__ colinvl)
{
    const int col = blockIdx.x * 256 + threadIdx.x;
    const int b = col >> 8, q = col & 255;
    float M = -INFINITY, L = 0.f;
    for (int ch = 0; ch < 16; ++ch) {
        int idx = (b * 16 + ch) * LQ_ + q;
        float m = pm[idx], l = pl[idx];
        float nM = fmaxf(M, m);
        L = L * __expf(M - nM) + l * __expf(m - nM);
        M = nM;
    }
    colm[col] = M; colinvl[col] = 1.0f / L;
}

// ---- G3: Tpart[s][b][d][q] = sum_{c in split s} ctx[c][d]*exp(sim[c][q]-colm[q])
// K-split 4-way for occupancy (1024 blocks = 4 waves/SIMD vs old 1), with
// T14 register prefetch of the next c-tile. Normalization moved to k_bnorm.
#define LDA3 66
#define G3SPLIT 4
#define G3CHUNK (LC_ / G3SPLIT)   // 512
__global__ __launch_bounds__(256) void k_g3(
    const f16* __restrict__ ctx16, const f16* __restrict__ sim16,
    const float* __restrict__ colm, float* __restrict__ Tpart)
{
    __shared__ f16 As[128 * LDA3];   // [d][c]
    __shared__ f16 Bs[64 * LDA3];    // [q][c]
    __shared__ float colm_s[64];
    const int b = blockIdx.x;
    const int combo = blockIdx.y;          // qt(0..3) + 4*dh(0..1)
    const int qt = combo & 3, dh = combo >> 2;
    const int q0 = qt * 64, d0 = dh * 128;
    const int cbeg = blockIdx.z * G3CHUNK;
    const int t = threadIdx.x, lane = t & 63, wv = t >> 6;
    const int wm_off = (wv >> 1) * 64, wn_off = (wv & 1) * 32;
    if (t < 64) colm_s[t] = colm[b * LQ_ + q0 + t];
    __syncthreads();
    const f16* Ab = ctx16 + (long long)b * LC_ * D_;
    const f16* Sb = sim16 + (long long)b * LC_ * LQ_;
    f32x4 acc[4][2] = {};
    const int acc_ = t >> 4, ad8 = (t & 15) * 8;   // A staging: c-row, d-col8
    const int bcc = t >> 3, bq8 = (t & 7) * 8;     // B staging: c-row, q-col8
    f16x8 ha[4], hb[2];
    #pragma unroll
    for (int p = 0; p < 4; ++p)
        ha[p] = *(const f16x8*)(Ab + (long long)(cbeg + acc_ + p * 16) * D_ + d0 + ad8);
    #pragma unroll
    for (int p = 0; p < 2; ++p)
        hb[p] = *(const f16x8*)(Sb + (long long)(cbeg + bcc + p * 32) * LQ_ + q0 + bq8);
    for (int c0 = cbeg; c0 < cbeg + G3CHUNK; c0 += 64) {
        #pragma unroll
        for (int p = 0; p < 4; ++p) {
            int cc = acc_ + p * 16;
            #pragma unroll
            for (int j = 0; j < 8; ++j)
                As[(ad8 + j) * LDA3 + cc] = ha[p][j];
        }
        #pragma unroll
        for (int p = 0; p < 2; ++p) {
            int cc = bcc + p * 32;
            #pragma unroll
            for (int j = 0; j < 8; ++j)
                Bs[(bq8 + j) * LDA3 + cc] = (f16)__expf((float)hb[p][j] - colm_s[bq8 + j]);
        }
        if (c0 + 64 < cbeg + G3CHUNK) {
            #pragma unroll
            for (int p = 0; p < 4; ++p)
                ha[p] = *(const f16x8*)(Ab + (long long)(c0 + 64 + acc_ + p * 16) * D_ + d0 + ad8);
            #pragma unroll
            for (int p = 0; p < 2; ++p)
                hb[p] = *(const f16x8*)(Sb + (long long)(c0 + 64 + bcc + p * 32) * LQ_ + q0 + bq8);
        }
        __syncthreads();
        #pragma unroll
        for (int kk = 0; kk < 64; kk += 32) {
            f16x8 af[4], bf[2];
            #pragma unroll
            for (int i = 0; i < 4; ++i)
                af[i] = *(const f16x8*)(As + (wm_off + i * 16 + (lane & 15)) * LDA3 + kk + (lane >> 4) * 8);
            #pragma unroll
            for (int j = 0; j < 2; ++j)
                bf[j] = *(const f16x8*)(Bs + (wn_off + j * 16 + (lane & 15)) * LDA3 + kk + (lane >> 4) * 8);
            #pragma unroll
            for (int i = 0; i < 4; ++i)
                #pragma unroll
                for (int j = 0; j < 2; ++j)
                    acc[i][j] = __builtin_amdgcn_mfma_f32_16x16x32_f16(af[i], bf[j], acc[i][j], 0, 0, 0);
        }
        __syncthreads();
    }
    float* Tb = Tpart + ((long long)blockIdx.z * B_ + b) * (LQ_ * D_);
    #pragma unroll
    for (int i = 0; i < 4; ++i) {
        #pragma unroll
        for (int r = 0; r < 4; ++r) {
            int d = d0 + wm_off + i * 16 + (lane >> 4) * 4 + r;
            float* orow = Tb + (long long)d * LQ_ + q0 + wn_off + (lane & 15);
            #pragma unroll
            for (int j = 0; j < 2; ++j)
                orow[j * 16] = acc[i][j][r];
        }
    }
}

// ---- BN: Bcat[256+d][q] = f16( colinvl[q] * sum_s Tpart[s][b][d][q] ) ----
__global__ __launch_bounds__(256) void k_bnorm(
    const float* __restrict__ Tpart, const float* __restrict__ colinvl,
    f16* __restrict__ Bcat)
{
    const long long i4 = ((long long)blockIdx.x * 256 + threadIdx.x) * 4;
    const int q = (int)(i4 & 255);
    const int d = (int)((i4 >> 8) & 255);
    const int b = (int)(i4 >> 16);
    float4 s = *(const float4*)(Tpart + i4);
    #pragma unroll
    for (int p = 1; p < G3SPLIT; ++p) {
        float4 v = *(const float4*)(Tpart + (long long)p * (B_ * LQ_ * D_) + i4);
        s.x += v.x; s.y += v.y; s.z += v.z; s.w += v.w;
    }
    float4 ci = *(const float4*)(colinvl + b * LQ_ + q);
    f16x4 h;
    h[0] = (f16)(s.x * ci.x); h[1] = (f16)(s.y * ci.y);
    h[2] = (f16)(s.z * ci.z); h[3] = (f16)(s.w * ci.w);
    *(f16x4*)(Bcat + (long long)b * 512 * LQ_ + (long long)(256 + d) * LQ_ + q) = h;
}

// ---- G23: [A | Bmat] = rowinvl * exp(sim16 - rowm) @ Bcat^T ----
// 128x128 tiling (2048 blocks) + T14 register prefetch of next k-tile.
__global__ __launch_bounds__(256) void k_g23(
    const f16* __restrict__ sim16, const float* __restrict__ rowm,
    const float* __restrict__ rowinvl, const f16* __restrict__ Bcat,
    float* __restrict__ outA, float* __restrict__ outB)
{
    __shared__ f16 As[128 * LDA1];
    __shared__ f16 Bs[128 * LDA1];
    const int b = blockIdx.z;
    const int c0 = blockIdx.x * 128, n0 = blockIdx.y * 128;
    const int t = threadIdx.x, lane = t & 63, wv = t >> 6;
    const int wm_off = (wv >> 1) * 64, wn_off = (wv & 1) * 64;
    const f16* Ab = sim16 + ((long long)b * LC_ + c0) * LQ_;
    const f16* Bb = Bcat + ((long long)b * 512 + n0) * LQ_;
    const int srow = t >> 2, scg = (t & 3) * 8;
    float rm[2];
    #pragma unroll
    for (int p = 0; p < 2; ++p) rm[p] = rowm[b * LC_ + c0 + srow + p * 64];
    f32x4 acc[4][4] = {};
    f16x8 ha[2], hb[2];
    #pragma unroll
    for (int p = 0; p < 2; ++p) {
        int r = srow + p * 64;
        ha[p] = *(const f16x8*)(Ab + (long long)r * LQ_ + scg);
        hb[p] = *(const f16x8*)(Bb + (long long)r * LQ_ + scg);
    }
    for (int k0 = 0; k0 < LQ_; k0 += 32) {
        #pragma unroll
        for (int p = 0; p < 2; ++p) {
            int r = srow + p * 64;
            f16x8 e;
            #pragma unroll
            for (int j = 0; j < 8; ++j) e[j] = (f16)__expf((float)ha[p][j] - rm[p]);
            *(f16x8*)(As + r * LDA1 + scg) = e;
            *(f16x8*)(Bs + r * LDA1 + scg) = hb[p];
        }
        if (k0 + 32 < LQ_) {
            #pragma unroll
            for (int p = 0; p < 2; ++p) {
                int r = srow + p * 64;
                ha[p] = *(const f16x8*)(Ab + (long long)r * LQ_ + k0 + 32 + scg);
                hb[p] = *(const f16x8*)(Bb + (long long)r * LQ_ + k0 + 32 + scg);
            }
        }
        __syncthreads();
        f16x8 af[4], bf[4];
        #pragma unroll
        for (int i = 0; i < 4; ++i)
            af[i] = *(const f16x8*)(As + (wm_off + i * 16 + (lane & 15)) * LDA1 + (lane >> 4) * 8);
        #pragma unroll
        for (int j = 0; j < 4; ++j)
            bf[j] = *(const f16x8*)(Bs + (wn_off + j * 16 + (lane & 15)) * LDA1 + (lane >> 4) * 8);
        #pragma unroll
        for (int i = 0; i < 4; ++i)
            #pragma unroll
            for (int j = 0; j < 4; ++j)
                acc[i][j] = __builtin_amdgcn_mfma_f32_16x16x32_f16(af[i], bf[j], acc[i][j], 0, 0, 0);
        __syncthreads();
    }
    float* outp = (n0 < 256) ? outA : outB;
    const int nbase = (n0 < 256) ? n0 : (n0 - 256);
    #pragma unroll
    for (int i = 0; i < 4; ++i) {
        #pragma unroll
        for (int r = 0; r < 4; ++r) {
            int c = c0 + wm_off + i * 16 + (lane >> 4) * 4 + r;
            float ri = rowinvl[b * LC_ + c];
            float* orow = outp + ((long long)b * LC_ + c) * D_ + nbase + wn_off + (lane & 15);
            #pragma unroll
            for (int j = 0; j < 4; ++j)
                orow[j * 16] = acc[i][j][r] * ri;
        }
    }
}

extern "C" void kernel_launch(void* const* d_in, const int* in_sizes, int n_in,
                              void* d_out, int out_size, void* d_ws, size_t ws_size,
                              hipStream_t stream) {
    const float* ctx   = (const float*)d_in[0];
    const float* qry   = (const float*)d_in[1];
    const int*   cmask = (const int*)d_in[2];
    const int*   qmask = (const int*)d_in[3];
    const float* w0    = (const float*)d_in[4];
    float* out = (float*)d_out;

    char* w = (char*)d_ws;
    float* sc      = (float*)w;  w += (long long)65536 * 4;
    float* sq      = (float*)w;  w += (long long)8192 * 4;
    float* rowm    = (float*)w;  w += (long long)65536 * 4;
    float* rowinvl = (float*)w;  w += (long long)65536 * 4;
    float* colm    = (float*)w;  w += (long long)8192 * 4;
    float* colinvl = (float*)w;  w += (long long)8192 * 4;
    float* pm      = (float*)w;  w += (long long)524288 * 4;
    float* pl      = (float*)w;  w += (long long)524288 * 4;
    f16*   sim16   = (f16*)w;    w += (long long)16777216 * 2;
    f16*   ctx16   = (f16*)w;    w += (long long)16777216 * 2;
    f16*   qrywm16 = (f16*)w;    w += (long long)2097152 * 2;
    f16*   Bcat    = (f16*)w;    w += (long long)4194304 * 2;
    float* Tpart   = (float*)w;  w += (long long)G3SPLIT * 2097152 * 4;

    k_prep<<<18432, 256, 0, stream>>>(ctx, qry, w0, ctx16, qrywm16, sc, sq);
    k_tq<<<dim3(4, 4, 32), 256, 0, stream>>>(qry, Bcat);
    k_g1<<<dim3(16, 1, 32), 256, 0, stream>>>(ctx16, qrywm16, sc, sq, cmask, qmask,
        sim16, rowm, rowinvl, pm, pl);
    k_colreduce<<<32, 256, 0, stream>>>(pm, pl, colm, colinvl);
    k_g3<<<dim3(32, 8, G3SPLIT), 256, 0, stream>>>(ctx16, sim16, colm, Tpart);
    k_bnorm<<<2048, 256, 0, stream>>>(Tpart, colinvl, Bcat);
    k_g23<<<dim3(16, 4, 32), 256, 0, stream>>>(sim16, rowm, rowinvl, Bcat,
        out, out + (long long)B_ * LC_ * D_);
}